// Round 9
// baseline (671.296 us; speedup 1.0000x reference)
//
#include <hip/hip_runtime.h>
#include <math.h>

#define GK 602
#define GH 128
#define GC 41
#define GCP 48     // padded class count for layer-2 aggregate
#define KPAD 608   // 19 k-tiles of 32
#define NKT 19
#define W1FN (NKT * 4096)   // W1F elements

typedef __bf16 bf16x8 __attribute__((ext_vector_type(8)));
typedef float f32x16 __attribute__((ext_vector_type(16)));

__device__ __forceinline__ unsigned short f2bf(float f) {
    __bf16 b = (__bf16)f;
    return __builtin_bit_cast(unsigned short, b);
}
__device__ __forceinline__ float bf2f(unsigned short u) {
    return __uint_as_float((unsigned int)u << 16);
}
__device__ __forceinline__ float bflo(unsigned int u) { return __uint_as_float(u << 16); }
__device__ __forceinline__ float bfhi(unsigned int u) { return __uint_as_float(u & 0xffff0000u); }

// direct-to-LDS DMA: HW writes wave-uniform base + lane*size; per-lane lds ptr
// must be linear in lane with stride == size (guide §5 / m97 pattern).
__device__ __forceinline__ void gl_lds16(const float* g, float* l) {
    __builtin_amdgcn_global_load_lds((const __attribute__((address_space(1))) void*)g,
                                     (__attribute__((address_space(3))) void*)l, 16, 0, 0);
}
__device__ __forceinline__ void gl_lds4(const float* g, float* l) {
    __builtin_amdgcn_global_load_lds((const __attribute__((address_space(1))) void*)g,
                                     (__attribute__((address_space(3))) void*)l, 4, 0, 0);
}

// ---------------- L1 role-split: prepW1F (blocks < nbPrep) || hist ----------------
// W1F layout (ushort idx): kt*4096 + nt*1024 + h*512 + lane*8 + j
//   element = W1[k][col], col = 32*nt + (lane&31), k = 32*kt + 16*h + 8*(lane>>5) + j
// k >= 602 zero-padded (NaN-safety for A k-overreads: garbage*0 = 0).

__global__ void k_pre(const float* __restrict__ W1, unsigned short* __restrict__ W1F,
                      const int* __restrict__ dst, int* __restrict__ counts,
                      int E, int nbPrep) {
    if ((int)blockIdx.x < nbPrep) {
        int i = blockIdx.x * 256 + threadIdx.x;
        if (i >= W1FN) return;
        int kt = i >> 12;
        int r  = i & 4095;
        int nt = r >> 10;
        int r2 = r & 1023;
        int bs = r2 >> 9;
        int r3 = r2 & 511;
        int ln = r3 >> 3;
        int j  = r3 & 7;
        int col = 32 * nt + (ln & 31);
        int k   = 32 * kt + 16 * bs + 8 * (ln >> 5) + j;
        float v = (k < GK) ? W1[(size_t)k * GH + col] : 0.f;
        W1F[i] = f2bf(v);
    } else {
        int g = (blockIdx.x - nbPrep) * 256 + threadIdx.x;
        int base = g * 4;
        if (((E & 3) == 0) && (base + 3 < E)) {
            int4 d4 = *(const int4*)(dst + base);
            atomicAdd(&counts[d4.x], 1);
            atomicAdd(&counts[d4.y], 1);
            atomicAdd(&counts[d4.z], 1);
            atomicAdd(&counts[d4.w], 1);
        } else {
#pragma unroll
            for (int j2 = 0; j2 < 4; ++j2) {
                int e = base + j2;
                if (e < E) atomicAdd(&counts[dst[e]], 1);
            }
        }
    }
}

// exclusive scan of counts -> row_ptr, 1024 elems/block, shuffle-based
__global__ void k_scan_a(const int* __restrict__ counts, int* __restrict__ row_ptr,
                         int* __restrict__ bsum, int n) {
    __shared__ int wsum[4];
    int t = threadIdx.x;
    int lane = t & 63;
    int wv = t >> 6;
    int base = blockIdx.x * 1024 + t * 4;
    int v[4];
    int s = 0;
#pragma unroll
    for (int j = 0; j < 4; ++j) {
        int idx = base + j;
        v[j] = (idx < n) ? counts[idx] : 0;
        s += v[j];
    }
    int incl = s;
#pragma unroll
    for (int o = 1; o < 64; o <<= 1) {
        int x = __shfl_up(incl, o);
        if (lane >= o) incl += x;
    }
    if (lane == 63) wsum[wv] = incl;
    __syncthreads();
    int woff = 0;
#pragma unroll
    for (int i = 0; i < 3; ++i) woff += (i < wv) ? wsum[i] : 0;
    if (t == 255) bsum[blockIdx.x] = woff + incl;
    int off = woff + incl - s;
#pragma unroll
    for (int j = 0; j < 4; ++j) {
        int idx = base + j;
        if (idx < n) row_ptr[idx] = off;
        off += v[j];
    }
}

// single-block exclusive scan of bsum (nb <= 256)
__global__ void k_scan_b(int* __restrict__ bsum, int nb) {
    __shared__ int sh[256];
    int t = threadIdx.x;
    int v = (t < nb) ? bsum[t] : 0;
    sh[t] = v;
    __syncthreads();
    for (int o = 1; o < 256; o <<= 1) {
        int x = (t >= o) ? sh[t - o] : 0;
        __syncthreads();
        sh[t] += x;
        __syncthreads();
    }
    if (t < nb) bsum[t] = sh[t] - v;
}

// finalize row_ptr, init cursor, compute dinv (fused)
__global__ void k_scan_c(int* __restrict__ row_ptr, const int* __restrict__ bsum,
                         const int* __restrict__ counts, float* __restrict__ dinv,
                         int* __restrict__ cursor, int n, int E) {
    int i = blockIdx.x * 256 + threadIdx.x;
    if (i < n) {
        int rp = row_ptr[i] + bsum[i >> 10];
        row_ptr[i] = rp;
        cursor[i] = rp;
        dinv[i] = rsqrtf((float)(counts[i] + 1));  // +1 self-loop
    }
    if (i == 0) row_ptr[n] = E;
}

// ---------------- L5 role-split: fill (blocks < nbF) || gemm1 ----------------
// Fill role FIRST: its 1563 blocks retire during gemm1's ramp-up instead of
// forming an LDS-throttled tail (r8: combined 174us > 98+50 sum-parts).
// gemm1: sequential-stream MFMA design (harness-verified r3): block owns 32
// consecutive rows = one contiguous 77056B slab of X staged linearly to LDS via
// global_load_lds; B fragments from the L2-resident fragment-ordered W1F table.

#define SLABF (32 * GK)        // 19264 floats per slab

__global__ __launch_bounds__(256, 2) void k_gemm1_fill(
        const float* __restrict__ X, const unsigned short* __restrict__ W1F,
        unsigned short* __restrict__ Y, int M,
        const int* __restrict__ src, const int* __restrict__ dst,
        const float* __restrict__ dinv, int* __restrict__ cursor,
        int2* __restrict__ meta, int E, int nbF) {
    if ((int)blockIdx.x < nbF) {
        // ---- fill role ----
        int g = blockIdx.x * 256 + threadIdx.x;
        int base = g * 4;
        if (((E & 3) == 0) && (base + 3 < E)) {
            int4 s4 = *(const int4*)(src + base);
            int4 d4 = *(const int4*)(dst + base);
            int ss[4] = {s4.x, s4.y, s4.z, s4.w};
            int dd[4] = {d4.x, d4.y, d4.z, d4.w};
#pragma unroll
            for (int j = 0; j < 4; ++j) {
                int p = atomicAdd(&cursor[dd[j]], 1);
                float w = dinv[ss[j]] * dinv[dd[j]];
                meta[p] = make_int2(ss[j], __float_as_int(w));
            }
        } else {
#pragma unroll
            for (int j = 0; j < 4; ++j) {
                int e = base + j;
                if (e < E) {
                    int s = src[e];
                    int d = dst[e];
                    int p = atomicAdd(&cursor[d], 1);
                    float w = dinv[s] * dinv[d];
                    meta[p] = make_int2(s, __float_as_int(w));
                }
            }
        }
        return;
    }

    // ---- gemm1 role ----
    __shared__ float As[SLABF + 16];   // 77056B slab + 64B zeroed pad
    int tid = threadIdx.x;
    int lane = tid & 63;
    int w = tid >> 6;
    int rowBase = (blockIdx.x - nbF) * 32;
    const float* slab = X + (size_t)rowBase * GK;

#pragma unroll
    for (int r = 0; r < 18; ++r) {
        int c = tid + 256 * r;                 // chunks 0..4607
        gl_lds16(slab + 4 * c, &As[4 * c]);
    }
    if (w < 3) {
        int c = 4608 + (w << 6) + lane;        // chunks 4608..4799
        gl_lds16(slab + 4 * c, &As[4 * c]);
    } else {
        int f = 19200 + lane;                  // floats 19200..19263 (last 256B)
        gl_lds4(slab + f, &As[f]);
    }
    if (tid < 16) As[SLABF + tid] = 0.f;       // finite pad for k-overread rows
    asm volatile("s_waitcnt vmcnt(0)" ::: "memory");
    __syncthreads();

    int arow = lane & 31;                      // A row within slab
    int kh = 8 * (lane >> 5);                  // 0 or 8
    const float* Ar = &As[arow * GK];
    const unsigned short* Wb = W1F + (size_t)w * 1024 + (size_t)lane * 8;

    f32x16 acc;
#pragma unroll
    for (int i = 0; i < 16; ++i) acc[i] = 0.f;

#pragma unroll
    for (int t = 0; t < NKT; ++t) {
        const unsigned short* Wt = Wb + (size_t)t * 4096;
        bf16x8 b0 = *(const bf16x8*)(Wt);          // k-half 0
        bf16x8 b1 = *(const bf16x8*)(Wt + 512);    // k-half 1
        const float* a0p = Ar + 32 * t + kh;
        float2 p0 = *(const float2*)(a0p + 0);
        float2 p1 = *(const float2*)(a0p + 2);
        float2 p2 = *(const float2*)(a0p + 4);
        float2 p3 = *(const float2*)(a0p + 6);
        const float* a1p = a0p + 16;
        float2 q0 = *(const float2*)(a1p + 0);
        float2 q1 = *(const float2*)(a1p + 2);
        float2 q2 = *(const float2*)(a1p + 4);
        float2 q3 = *(const float2*)(a1p + 6);
        bf16x8 af0, af1;
        af0[0] = (__bf16)p0.x; af0[1] = (__bf16)p0.y;
        af0[2] = (__bf16)p1.x; af0[3] = (__bf16)p1.y;
        af0[4] = (__bf16)p2.x; af0[5] = (__bf16)p2.y;
        af0[6] = (__bf16)p3.x; af0[7] = (__bf16)p3.y;
        af1[0] = (__bf16)q0.x; af1[1] = (__bf16)q0.y;
        af1[2] = (__bf16)q1.x; af1[3] = (__bf16)q1.y;
        af1[4] = (__bf16)q2.x; af1[5] = (__bf16)q2.y;
        af1[6] = (__bf16)q3.x; af1[7] = (__bf16)q3.y;
        acc = __builtin_amdgcn_mfma_f32_32x32x16_bf16(af0, b0, acc, 0, 0, 0);
        acc = __builtin_amdgcn_mfma_f32_32x32x16_bf16(af1, b1, acc, 0, 0, 0);
    }

    // epilogue: C/D layout col=lane&31, row=(reg&3)+8*(reg>>2)+4*(lane>>5)
    int gcol = 32 * w + (lane & 31);
#pragma unroll
    for (int reg = 0; reg < 16; ++reg) {
        int rrow = (reg & 3) + 8 * (reg >> 2) + 4 * (lane >> 5);
        int grow = rowBase + rrow;
        if (grow < M) Y[(size_t)grow * GH + gcol] = f2bf(acc[reg]);
    }
}

// ---------------- layer-1 aggregate: dual-dst interleaved 8+8 batching ----------------
// Each wave owns two ADJACENT dsts (CSR ranges contiguous -> sequential meta).
// Joint loop keeps 16 gathers outstanding even for deg 8..15 rows (Poisson 16:
// ~50% of edges previously fell to shallow 8/4/1 drains); remainders use the
// proven 16/8/4/1 ladder.

__device__ __forceinline__ void agg1_drain(const unsigned int* __restrict__ H,
                                           const int2* __restrict__ meta, int lane,
                                           int e, int end, float& a0, float& a1) {
    for (; e + 16 <= end; e += 16) {
        int2 m[16];
        unsigned int u[16];
#pragma unroll
        for (int j = 0; j < 16; ++j) m[j] = meta[e + j];
#pragma unroll
        for (int j = 0; j < 16; ++j) u[j] = H[(size_t)m[j].x * 64 + lane];
#pragma unroll
        for (int j = 0; j < 16; ++j) {
            float wj = __int_as_float(m[j].y);
            a0 = fmaf(wj, bflo(u[j]), a0);
            a1 = fmaf(wj, bfhi(u[j]), a1);
        }
    }
    if (e + 8 <= end) {
        int2 m[8];
        unsigned int u[8];
#pragma unroll
        for (int j = 0; j < 8; ++j) m[j] = meta[e + j];
#pragma unroll
        for (int j = 0; j < 8; ++j) u[j] = H[(size_t)m[j].x * 64 + lane];
#pragma unroll
        for (int j = 0; j < 8; ++j) {
            float wj = __int_as_float(m[j].y);
            a0 = fmaf(wj, bflo(u[j]), a0);
            a1 = fmaf(wj, bfhi(u[j]), a1);
        }
        e += 8;
    }
    if (e + 4 <= end) {
        int2 m[4];
        unsigned int u[4];
#pragma unroll
        for (int j = 0; j < 4; ++j) m[j] = meta[e + j];
#pragma unroll
        for (int j = 0; j < 4; ++j) u[j] = H[(size_t)m[j].x * 64 + lane];
#pragma unroll
        for (int j = 0; j < 4; ++j) {
            float wj = __int_as_float(m[j].y);
            a0 = fmaf(wj, bflo(u[j]), a0);
            a1 = fmaf(wj, bfhi(u[j]), a1);
        }
        e += 4;
    }
    for (; e < end; ++e) {
        int2 m = meta[e];
        unsigned int u = H[(size_t)m.x * 64 + lane];
        float wj = __int_as_float(m.y);
        a0 = fmaf(wj, bflo(u), a0);
        a1 = fmaf(wj, bfhi(u), a1);
    }
}

__global__ __launch_bounds__(256) void k_agg1(const unsigned int* __restrict__ H,
                                              unsigned int* __restrict__ O,
                                              const int* __restrict__ row_ptr,
                                              const int2* __restrict__ meta,
                                              const float* __restrict__ dinv,
                                              const float* __restrict__ bias, int n) {
    int wv = threadIdx.x >> 6;
    int lane = threadIdx.x & 63;
    int d0 = blockIdx.x * 8 + wv * 2;
    int d1 = d0 + 1;
    if (d0 >= n) return;
    bool has1 = (d1 < n);
    float dd0 = dinv[d0];
    float dd1 = has1 ? dinv[d1] : 0.f;
    int b0 = row_ptr[d0], e0 = row_ptr[d0 + 1];
    int b1 = has1 ? row_ptr[d1] : 0;
    int e1 = has1 ? row_ptr[d1 + 1] : 0;
    unsigned int v0 = H[(size_t)d0 * 64 + lane];
    unsigned int v1 = H[(size_t)(has1 ? d1 : d0) * 64 + lane];
    float a00 = dd0 * dd0 * bflo(v0), a01 = dd0 * dd0 * bfhi(v0);
    float a10 = dd1 * dd1 * bflo(v1), a11 = dd1 * dd1 * bfhi(v1);

    // joint deep phase: 8 + 8 outstanding across the two streams
    while (b0 + 8 <= e0 && b1 + 8 <= e1) {
        int2 m0[8], m1[8];
        unsigned int u0[8], u1[8];
#pragma unroll
        for (int j = 0; j < 8; ++j) m0[j] = meta[b0 + j];
#pragma unroll
        for (int j = 0; j < 8; ++j) m1[j] = meta[b1 + j];
#pragma unroll
        for (int j = 0; j < 8; ++j) u0[j] = H[(size_t)m0[j].x * 64 + lane];
#pragma unroll
        for (int j = 0; j < 8; ++j) u1[j] = H[(size_t)m1[j].x * 64 + lane];
#pragma unroll
        for (int j = 0; j < 8; ++j) {
            float w0 = __int_as_float(m0[j].y);
            float w1 = __int_as_float(m1[j].y);
            a00 = fmaf(w0, bflo(u0[j]), a00);
            a01 = fmaf(w0, bfhi(u0[j]), a01);
            a10 = fmaf(w1, bflo(u1[j]), a10);
            a11 = fmaf(w1, bfhi(u1[j]), a11);
        }
        b0 += 8;
        b1 += 8;
    }
    agg1_drain(H, meta, lane, b0, e0, a00, a01);
    if (has1) agg1_drain(H, meta, lane, b1, e1, a10, a11);

    float bl = bias[2 * lane], bh = bias[2 * lane + 1];
    a00 = fmaxf(a00 + bl, 0.f);
    a01 = fmaxf(a01 + bh, 0.f);
    O[(size_t)d0 * 64 + lane] = (unsigned int)f2bf(a00) | ((unsigned int)f2bf(a01) << 16);
    if (has1) {
        a10 = fmaxf(a10 + bl, 0.f);
        a11 = fmaxf(a11 + bh, 0.f);
        O[(size_t)d1 * 64 + lane] = (unsigned int)f2bf(a10) | ((unsigned int)f2bf(a11) << 16);
    }
}

// ---------------- layer-2 transform first: G = relu(H1) @ W2, bf16 out, padded to 48 ----------------

__global__ __launch_bounds__(256) void k_gemm2t(const unsigned int* __restrict__ Hb,
                                                const float* __restrict__ W2,
                                                unsigned short* __restrict__ G, int n) {
    __shared__ float ws[128][GCP];
    for (int i = threadIdx.x; i < 128 * GCP; i += 256) {
        int k = i / GCP;
        int c = i - k * GCP;
        ws[k][c] = (c < GC) ? W2[k * GC + c] : 0.f;
    }
    __syncthreads();
    int r0 = blockIdx.x * 512 + threadIdx.x;
    int r1 = r0 + 256;
    bool v0 = r0 < n, v1 = r1 < n;
    float acc0[GCP], acc1[GCP];
#pragma unroll
    for (int c = 0; c < GCP; ++c) { acc0[c] = 0.f; acc1[c] = 0.f; }
    const uint2* h0 = (const uint2*)(Hb + (size_t)(v0 ? r0 : 0) * 64);
    const uint2* h1 = (const uint2*)(Hb + (size_t)(v1 ? r1 : 0) * 64);
    for (int q = 0; q < 32; ++q) {
        uint2 ua = h0[q];
        uint2 ub = h1[q];
        float va[4] = {bflo(ua.x), bfhi(ua.x), bflo(ua.y), bfhi(ua.y)};
        float vb[4] = {bflo(ub.x), bfhi(ub.x), bflo(ub.y), bfhi(ub.y)};
#pragma unroll
        for (int j = 0; j < 4; ++j) {
            int k = 4 * q + j;
#pragma unroll
            for (int cq = 0; cq < GCP / 4; ++cq) {
                float4 wv = *(const float4*)&ws[k][4 * cq];
                acc0[4 * cq + 0] = fmaf(va[j], wv.x, acc0[4 * cq + 0]);
                acc0[4 * cq + 1] = fmaf(va[j], wv.y, acc0[4 * cq + 1]);
                acc0[4 * cq + 2] = fmaf(va[j], wv.z, acc0[4 * cq + 2]);
                acc0[4 * cq + 3] = fmaf(va[j], wv.w, acc0[4 * cq + 3]);
                acc1[4 * cq + 0] = fmaf(vb[j], wv.x, acc1[4 * cq + 0]);
                acc1[4 * cq + 1] = fmaf(vb[j], wv.y, acc1[4 * cq + 1]);
                acc1[4 * cq + 2] = fmaf(vb[j], wv.z, acc1[4 * cq + 2]);
                acc1[4 * cq + 3] = fmaf(vb[j], wv.w, acc1[4 * cq + 3]);
            }
        }
    }
    if (v0) {
#pragma unroll
        for (int c = 0; c < GCP; ++c) G[(size_t)r0 * GCP + c] = f2bf(acc0[c]);
    }
    if (v1) {
#pragma unroll
        for (int c = 0; c < GCP; ++c) G[(size_t)r1 * GCP + c] = f2bf(acc1[c]);
    }
}

// ---------------- layer-2 aggregate: dual-dst interleaved, + log_softmax ----------------

__device__ __forceinline__ void agg2_drain(const unsigned short* __restrict__ G,
                                           const int2* __restrict__ meta, int gl,
                                           int e, int end, float& a) {
    for (; e + 16 <= end; e += 16) {
        int2 m[16];
        unsigned short u[16];
#pragma unroll
        for (int j = 0; j < 16; ++j) m[j] = meta[e + j];
#pragma unroll
        for (int j = 0; j < 16; ++j) u[j] = G[(size_t)m[j].x * GCP + gl];
#pragma unroll
        for (int j = 0; j < 16; ++j) a = fmaf(__int_as_float(m[j].y), bf2f(u[j]), a);
    }
    if (e + 8 <= end) {
        int2 m[8];
        unsigned short u[8];
#pragma unroll
        for (int j = 0; j < 8; ++j) m[j] = meta[e + j];
#pragma unroll
        for (int j = 0; j < 8; ++j) u[j] = G[(size_t)m[j].x * GCP + gl];
#pragma unroll
        for (int j = 0; j < 8; ++j) a = fmaf(__int_as_float(m[j].y), bf2f(u[j]), a);
        e += 8;
    }
    if (e + 4 <= end) {
        int2 m[4];
        unsigned short u[4];
#pragma unroll
        for (int j = 0; j < 4; ++j) m[j] = meta[e + j];
#pragma unroll
        for (int j = 0; j < 4; ++j) u[j] = G[(size_t)m[j].x * GCP + gl];
#pragma unroll
        for (int j = 0; j < 4; ++j) a = fmaf(__int_as_float(m[j].y), bf2f(u[j]), a);
        e += 4;
    }
    for (; e < end; ++e) {
        int2 m = meta[e];
        a = fmaf(__int_as_float(m.y), bf2f(G[(size_t)m.x * GCP + gl]), a);
    }
}

__global__ __launch_bounds__(256) void k_agg2(const unsigned short* __restrict__ G,
                                              float* __restrict__ out,
                                              const int* __restrict__ row_ptr,
                                              const int2* __restrict__ meta,
                                              const float* __restrict__ dinv,
                                              const float* __restrict__ b2, int n) {
    int wv = threadIdx.x >> 6;
    int lane = threadIdx.x & 63;
    int gl = (lane < GCP) ? lane : (GCP - 1);
    int d0 = blockIdx.x * 8 + wv * 2;
    int d1 = d0 + 1;
    if (d0 >= n) return;
    bool has1 = (d1 < n);
    float dd0 = dinv[d0];
    float dd1 = has1 ? dinv[d1] : 0.f;
    int b0 = row_ptr[d0], e0 = row_ptr[d0 + 1];
    int b1 = has1 ? row_ptr[d1] : 0;
    int e1 = has1 ? row_ptr[d1 + 1] : 0;
    float a0 = dd0 * dd0 * bf2f(G[(size_t)d0 * GCP + gl]);
    float a1 = dd1 * dd1 * bf2f(G[(size_t)(has1 ? d1 : d0) * GCP + gl]);

    while (b0 + 8 <= e0 && b1 + 8 <= e1) {
        int2 m0[8], m1[8];
        unsigned short u0[8], u1[8];
#pragma unroll
        for (int j = 0; j < 8; ++j) m0[j] = meta[b0 + j];
#pragma unroll
        for (int j = 0; j < 8; ++j) m1[j] = meta[b1 + j];
#pragma unroll
        for (int j = 0; j < 8; ++j) u0[j] = G[(size_t)m0[j].x * GCP + gl];
#pragma unroll
        for (int j = 0; j < 8; ++j) u1[j] = G[(size_t)m1[j].x * GCP + gl];
#pragma unroll
        for (int j = 0; j < 8; ++j) {
            a0 = fmaf(__int_as_float(m0[j].y), bf2f(u0[j]), a0);
            a1 = fmaf(__int_as_float(m1[j].y), bf2f(u1[j]), a1);
        }
        b0 += 8;
        b1 += 8;
    }
    agg2_drain(G, meta, gl, b0, e0, a0);
    if (has1) agg2_drain(G, meta, gl, b1, e1, a1);

    // epilogue d0
    {
        float logit = (lane < GC) ? (a0 + b2[lane]) : -INFINITY;
        float mx = logit;
#pragma unroll
        for (int off = 32; off; off >>= 1) mx = fmaxf(mx, __shfl_xor(mx, off));
        float ex = (lane < GC) ? __expf(logit - mx) : 0.f;
        float sm = ex;
#pragma unroll
        for (int off = 32; off; off >>= 1) sm += __shfl_xor(sm, off);
        if (lane < GC) out[(size_t)d0 * GC + lane] = logit - mx - __logf(sm);
    }
    // epilogue d1
    if (has1) {
        float logit = (lane < GC) ? (a1 + b2[lane]) : -INFINITY;
        float mx = logit;
#pragma unroll
        for (int off = 32; off; off >>= 1) mx = fmaxf(mx, __shfl_xor(mx, off));
        float ex = (lane < GC) ? __expf(logit - mx) : 0.f;
        float sm = ex;
#pragma unroll
        for (int off = 32; off; off >>= 1) sm += __shfl_xor(sm, off);
        if (lane < GC) out[(size_t)d1 * GC + lane] = logit - mx - __logf(sm);
    }
}

// ---------------- launch ----------------

static inline size_t alignup256(size_t x) { return (x + 255) & ~(size_t)255; }

extern "C" void kernel_launch(void* const* d_in, const int* in_sizes, int n_in,
                              void* d_out, int out_size, void* d_ws, size_t ws_size,
                              hipStream_t stream) {
    const float* x  = (const float*)d_in[0];
    const int*   ei = (const int*)d_in[1];
    const float* W1 = (const float*)d_in[2];
    const float* b1 = (const float*)d_in[3];
    const float* W2 = (const float*)d_in[4];
    const float* b2 = (const float*)d_in[5];
    float* out = (float*)d_out;

    const int n = in_sizes[0] / GK;   // 100000
    const int E = in_sizes[1] / 2;    // 1600000
    const int* src = ei;
    const int* dst = ei + E;

    char* w = (char*)d_ws;
    char* p;
    p = w; w += alignup256((size_t)n * 4);            float* dinv  = (float*)p;
    p = w; w += alignup256((size_t)n * 4);            int* counts  = (int*)p;
    p = w; w += alignup256((size_t)n * 4);            int* cursor  = (int*)p;
    p = w; w += alignup256((size_t)(n + 1) * 4);      int* row_ptr = (int*)p;
    p = w; w += alignup256(1024 * 4);                 int* bsum    = (int*)p;
    p = w; w += alignup256((size_t)E * 8);            int2* meta   = (int2*)p;
    p = w; w += alignup256((size_t)GH * KPAD * 2);    unsigned short* W1F = (unsigned short*)p;
    p = w; w += alignup256((size_t)n * GH * 2);       unsigned short* bufA = (unsigned short*)p; // bf16 H1
    p = w; w += alignup256((size_t)n * GH * 2);       unsigned short* bufB = (unsigned short*)p; // bf16 relu(agg1)
    p = w; w += alignup256((size_t)n * GCP * 2);      unsigned short* G    = (unsigned short*)p; // bf16 H1relu@W2

    hipMemsetAsync(counts, 0, (size_t)n * 4, stream);

    int gN = (n + 255) / 256;
    int nb = (n + 1023) / 1024;
    int nbPrep = (W1FN + 255) / 256;          // 304
    int nbHist = (E / 4 + 255) / 256;         // 1563 (E divisible by 4)
    int nbG    = (n + 31) / 32;               // 3125

    k_pre<<<nbPrep + nbHist, 256, 0, stream>>>(W1, W1F, dst, counts, E, nbPrep);
    k_scan_a<<<nb, 256, 0, stream>>>(counts, row_ptr, bsum, n);
    k_scan_b<<<1, 256, 0, stream>>>(bsum, nb);
    k_scan_c<<<gN, 256, 0, stream>>>(row_ptr, bsum, counts, dinv, cursor, n, E);

    k_gemm1_fill<<<nbHist + nbG, 256, 0, stream>>>(x, W1F, bufA, n,
                                                   src, dst, dinv, cursor, meta, E, nbHist);
    k_agg1<<<(n + 7) / 8, 256, 0, stream>>>((const unsigned int*)bufA, (unsigned int*)bufB,
                                            row_ptr, meta, dinv, b1, n);
    k_gemm2t<<<(n + 511) / 512, 256, 0, stream>>>((const unsigned int*)bufB, W2, G, n);
    k_agg2<<<(n + 7) / 8, 256, 0, stream>>>(G, out, row_ptr, meta, dinv, b2, n);
}

// Round 10
// 668.551 us; speedup vs baseline: 1.0041x; 1.0041x over previous
//
#include <hip/hip_runtime.h>
#include <math.h>

#define GK 602
#define GH 128
#define GC 41
#define GCP 48     // padded class count for layer-2 aggregate
#define NKT 19
#define W1FN (NKT * 8 * 512)   // 16x16 fragment table: 19 t x 8 nt x 64 lanes x 8 = 77824

typedef __bf16 bf16x8 __attribute__((ext_vector_type(8)));
typedef float f32x4 __attribute__((ext_vector_type(4)));

__device__ __forceinline__ unsigned short f2bf(float f) {
    __bf16 b = (__bf16)f;
    return __builtin_bit_cast(unsigned short, b);
}
__device__ __forceinline__ float bf2f(unsigned short u) {
    return __uint_as_float((unsigned int)u << 16);
}
__device__ __forceinline__ float bflo(unsigned int u) { return __uint_as_float(u << 16); }
__device__ __forceinline__ float bfhi(unsigned int u) { return __uint_as_float(u & 0xffff0000u); }

// direct-to-LDS DMA: dest = wave-uniform base + lane*16 (linear); SOURCE is per-lane free.
__device__ __forceinline__ void gl_lds16(const float* g, float* l) {
    __builtin_amdgcn_global_load_lds((const __attribute__((address_space(1))) void*)g,
                                     (__attribute__((address_space(3))) void*)l, 16, 0, 0);
}

// ---------------- L1 role-split: prepW1F (blocks < nbPrep) || hist ----------------
// W1F (16x16 fragment order, ushort idx): t*4096 + nt*512 + lane*8 + j
//   element = W1[k][col], col = 16*nt + (lane&15), k = 32*t + 8*(lane>>4) + j
// k >= 602 zero-padded (NaN-safety for A k-overreads: garbage*0 = 0).

__global__ void k_pre(const float* __restrict__ W1, unsigned short* __restrict__ W1F,
                      const int* __restrict__ dst, int* __restrict__ counts,
                      int E, int nbPrep) {
    if ((int)blockIdx.x < nbPrep) {
        int i = blockIdx.x * 256 + threadIdx.x;
        if (i >= W1FN) return;
        int t  = i >> 12;
        int r  = i & 4095;
        int nt = r >> 9;
        int r2 = r & 511;
        int ln = r2 >> 3;
        int j  = r2 & 7;
        int col = 16 * nt + (ln & 15);
        int k   = 32 * t + 8 * (ln >> 4) + j;
        float v = (k < GK) ? W1[(size_t)k * GH + col] : 0.f;
        W1F[i] = f2bf(v);
    } else {
        int g = (blockIdx.x - nbPrep) * 256 + threadIdx.x;
        int base = g * 4;
        if (((E & 3) == 0) && (base + 3 < E)) {
            int4 d4 = *(const int4*)(dst + base);
            atomicAdd(&counts[d4.x], 1);
            atomicAdd(&counts[d4.y], 1);
            atomicAdd(&counts[d4.z], 1);
            atomicAdd(&counts[d4.w], 1);
        } else {
#pragma unroll
            for (int j2 = 0; j2 < 4; ++j2) {
                int e = base + j2;
                if (e < E) atomicAdd(&counts[dst[e]], 1);
            }
        }
    }
}

// exclusive scan of counts -> row_ptr, 1024 elems/block, shuffle-based
__global__ void k_scan_a(const int* __restrict__ counts, int* __restrict__ row_ptr,
                         int* __restrict__ bsum, int n) {
    __shared__ int wsum[4];
    int t = threadIdx.x;
    int lane = t & 63;
    int wv = t >> 6;
    int base = blockIdx.x * 1024 + t * 4;
    int v[4];
    int s = 0;
#pragma unroll
    for (int j = 0; j < 4; ++j) {
        int idx = base + j;
        v[j] = (idx < n) ? counts[idx] : 0;
        s += v[j];
    }
    int incl = s;
#pragma unroll
    for (int o = 1; o < 64; o <<= 1) {
        int x = __shfl_up(incl, o);
        if (lane >= o) incl += x;
    }
    if (lane == 63) wsum[wv] = incl;
    __syncthreads();
    int woff = 0;
#pragma unroll
    for (int i = 0; i < 3; ++i) woff += (i < wv) ? wsum[i] : 0;
    if (t == 255) bsum[blockIdx.x] = woff + incl;
    int off = woff + incl - s;
#pragma unroll
    for (int j = 0; j < 4; ++j) {
        int idx = base + j;
        if (idx < n) row_ptr[idx] = off;
        off += v[j];
    }
}

// single-block exclusive scan of bsum (nb <= 256)
__global__ void k_scan_b(int* __restrict__ bsum, int nb) {
    __shared__ int sh[256];
    int t = threadIdx.x;
    int v = (t < nb) ? bsum[t] : 0;
    sh[t] = v;
    __syncthreads();
    for (int o = 1; o < 256; o <<= 1) {
        int x = (t >= o) ? sh[t - o] : 0;
        __syncthreads();
        sh[t] += x;
        __syncthreads();
    }
    if (t < nb) bsum[t] = sh[t] - v;
}

// finalize row_ptr, init cursor, compute dinv (fused)
__global__ void k_scan_c(int* __restrict__ row_ptr, const int* __restrict__ bsum,
                         const int* __restrict__ counts, float* __restrict__ dinv,
                         int* __restrict__ cursor, int n, int E) {
    int i = blockIdx.x * 256 + threadIdx.x;
    if (i < n) {
        int rp = row_ptr[i] + bsum[i >> 10];
        row_ptr[i] = rp;
        cursor[i] = rp;
        dinv[i] = rsqrtf((float)(counts[i] + 1));  // +1 self-loop
    }
    if (i == 0) row_ptr[n] = E;
}

// ---------------- L5 role-split: fill (blocks < nbF) || gemm1 (16-row slabs) ----------------
// gemm1 v2: block owns 16 CONSECUTIVE rows (40960B staged LDS incl. tail overstage,
// clamped sources) -> EXACTLY 4 blocks/CU (vs 2 at 77KB): twice the independent
// block phases to break stage/compute convoying (r9: occupancy 20%, 1.54 TB/s).
// MFMA 16x16x32: A row=lane&15, k=8*(lane>>4)+j; B col=lane&15 (fragment table);
// C/D col=lane&15, row=4*(lane>>4)+reg (m89-verified layout).

#define STAGEF 10240           // floats staged (2560 chunks, 10 full rounds of 256)

__global__ __launch_bounds__(256, 4) void k_gemm1_fill(
        const float* __restrict__ X, const unsigned short* __restrict__ W1F,
        unsigned short* __restrict__ Y, int M,
        const int* __restrict__ src, const int* __restrict__ dst,
        const float* __restrict__ dinv, int* __restrict__ cursor,
        int2* __restrict__ meta, int E, int nbF) {
    __shared__ float As[STAGEF];   // 40960B; 4 blocks/CU = 160KB exactly
    if ((int)blockIdx.x < nbF) {
        // ---- fill role ----
        int g = blockIdx.x * 256 + threadIdx.x;
        int base = g * 4;
        if (((E & 3) == 0) && (base + 3 < E)) {
            int4 s4 = *(const int4*)(src + base);
            int4 d4 = *(const int4*)(dst + base);
            int ss[4] = {s4.x, s4.y, s4.z, s4.w};
            int dd[4] = {d4.x, d4.y, d4.z, d4.w};
#pragma unroll
            for (int j = 0; j < 4; ++j) {
                int p = atomicAdd(&cursor[dd[j]], 1);
                float w = dinv[ss[j]] * dinv[dd[j]];
                meta[p] = make_int2(ss[j], __float_as_int(w));
            }
        } else {
#pragma unroll
            for (int j = 0; j < 4; ++j) {
                int e = base + j;
                if (e < E) {
                    int s = src[e];
                    int d = dst[e];
                    int p = atomicAdd(&cursor[d], 1);
                    float w = dinv[s] * dinv[d];
                    meta[p] = make_int2(s, __float_as_int(w));
                }
            }
        }
        return;
    }

    // ---- gemm1 role ----
    int tid = threadIdx.x;
    int lane = tid & 63;
    int w = tid >> 6;
    int rowBase = (blockIdx.x - nbF) * 16;
    const float* slab = X + (size_t)rowBase * GK;
    const float* xlim = X + (size_t)M * GK - 4;   // last valid 16B chunk start

    // stage 2560 chunks linearly; overstage past the 9632-float slab is covered
    // by clamped per-lane sources (finite data; consumed only by zero-padded B)
#pragma unroll
    for (int r = 0; r < 10; ++r) {
        int c = tid + 256 * r;
        const float* s = slab + 4 * c;
        if (s > xlim) s = xlim;
        gl_lds16(s, &As[4 * c]);
    }
    asm volatile("s_waitcnt vmcnt(0)" ::: "memory");
    __syncthreads();

    int arow = lane & 15;          // A row
    int kh = 8 * (lane >> 4);      // k sub-offset: 0,8,16,24
    const float* Ar = &As[arow * GK];
    const unsigned short* Wb = W1F + (size_t)lane * 8;

    f32x4 acc0, acc1;
#pragma unroll
    for (int i = 0; i < 4; ++i) { acc0[i] = 0.f; acc1[i] = 0.f; }

#pragma unroll
    for (int t = 0; t < NKT; ++t) {
        const float* ap = Ar + 32 * t + kh;
        float2 p0 = *(const float2*)(ap + 0);
        float2 p1 = *(const float2*)(ap + 2);
        float2 p2 = *(const float2*)(ap + 4);
        float2 p3 = *(const float2*)(ap + 6);
        bf16x8 af;
        af[0] = (__bf16)p0.x; af[1] = (__bf16)p0.y;
        af[2] = (__bf16)p1.x; af[3] = (__bf16)p1.y;
        af[4] = (__bf16)p2.x; af[5] = (__bf16)p2.y;
        af[6] = (__bf16)p3.x; af[7] = (__bf16)p3.y;
        bf16x8 b0 = *(const bf16x8*)(Wb + (size_t)(8 * t + 2 * w) * 512);
        bf16x8 b1 = *(const bf16x8*)(Wb + (size_t)(8 * t + 2 * w + 1) * 512);
        acc0 = __builtin_amdgcn_mfma_f32_16x16x32_bf16(af, b0, acc0, 0, 0, 0);
        acc1 = __builtin_amdgcn_mfma_f32_16x16x32_bf16(af, b1, acc1, 0, 0, 0);
    }

    // epilogue: C/D col=lane&15, row=4*(lane>>4)+reg
    int rbase = rowBase + 4 * (lane >> 4);
    int c0 = 16 * (2 * w) + (lane & 15);
    int c1 = 16 * (2 * w + 1) + (lane & 15);
#pragma unroll
    for (int reg = 0; reg < 4; ++reg) {
        int grow = rbase + reg;
        if (grow < M) {
            Y[(size_t)grow * GH + c0] = f2bf(acc0[reg]);
            Y[(size_t)grow * GH + c1] = f2bf(acc1[reg]);
        }
    }
}

// ---------------- layer-1 aggregate: 128-wide bf16 gather, unroll-16 MLP (r8-verified) ----------------

__global__ __launch_bounds__(256) void k_agg1(const unsigned int* __restrict__ H,
                                              unsigned int* __restrict__ O,
                                              const int* __restrict__ row_ptr,
                                              const int2* __restrict__ meta,
                                              const float* __restrict__ dinv,
                                              const float* __restrict__ bias, int n) {
    int wv = threadIdx.x >> 6;
    int lane = threadIdx.x & 63;
    int d = blockIdx.x * 4 + wv;
    if (d >= n) return;
    float dd = dinv[d];
    int beg = row_ptr[d], end = row_ptr[d + 1];
    unsigned int v = H[(size_t)d * 64 + lane];
    float sw = dd * dd;
    float a0 = sw * bflo(v);
    float a1 = sw * bfhi(v);
    int e = beg;
    for (; e + 16 <= end; e += 16) {
        int2 m[16];
        unsigned int u[16];
#pragma unroll
        for (int j = 0; j < 16; ++j) m[j] = meta[e + j];
#pragma unroll
        for (int j = 0; j < 16; ++j) u[j] = H[(size_t)m[j].x * 64 + lane];
#pragma unroll
        for (int j = 0; j < 16; ++j) {
            float wj = __int_as_float(m[j].y);
            a0 = fmaf(wj, bflo(u[j]), a0);
            a1 = fmaf(wj, bfhi(u[j]), a1);
        }
    }
    if (e + 8 <= end) {
        int2 m[8];
        unsigned int u[8];
#pragma unroll
        for (int j = 0; j < 8; ++j) m[j] = meta[e + j];
#pragma unroll
        for (int j = 0; j < 8; ++j) u[j] = H[(size_t)m[j].x * 64 + lane];
#pragma unroll
        for (int j = 0; j < 8; ++j) {
            float wj = __int_as_float(m[j].y);
            a0 = fmaf(wj, bflo(u[j]), a0);
            a1 = fmaf(wj, bfhi(u[j]), a1);
        }
        e += 8;
    }
    if (e + 4 <= end) {
        int2 m[4];
        unsigned int u[4];
#pragma unroll
        for (int j = 0; j < 4; ++j) m[j] = meta[e + j];
#pragma unroll
        for (int j = 0; j < 4; ++j) u[j] = H[(size_t)m[j].x * 64 + lane];
#pragma unroll
        for (int j = 0; j < 4; ++j) {
            float wj = __int_as_float(m[j].y);
            a0 = fmaf(wj, bflo(u[j]), a0);
            a1 = fmaf(wj, bfhi(u[j]), a1);
        }
        e += 4;
    }
    for (; e < end; ++e) {
        int2 m = meta[e];
        unsigned int u = H[(size_t)m.x * 64 + lane];
        float wj = __int_as_float(m.y);
        a0 = fmaf(wj, bflo(u), a0);
        a1 = fmaf(wj, bfhi(u), a1);
    }
    a0 = fmaxf(a0 + bias[2 * lane], 0.f);
    a1 = fmaxf(a1 + bias[2 * lane + 1], 0.f);
    O[(size_t)d * 64 + lane] = (unsigned int)f2bf(a0) | ((unsigned int)f2bf(a1) << 16);
}

// ---------------- layer-2 transform first: G = relu(H1) @ W2, bf16 out, padded to 48 ----------------

__global__ __launch_bounds__(256) void k_gemm2t(const unsigned int* __restrict__ Hb,
                                                const float* __restrict__ W2,
                                                unsigned short* __restrict__ G, int n) {
    __shared__ float ws[128][GCP];
    for (int i = threadIdx.x; i < 128 * GCP; i += 256) {
        int k = i / GCP;
        int c = i - k * GCP;
        ws[k][c] = (c < GC) ? W2[k * GC + c] : 0.f;
    }
    __syncthreads();
    int r0 = blockIdx.x * 512 + threadIdx.x;
    int r1 = r0 + 256;
    bool v0 = r0 < n, v1 = r1 < n;
    float acc0[GCP], acc1[GCP];
#pragma unroll
    for (int c = 0; c < GCP; ++c) { acc0[c] = 0.f; acc1[c] = 0.f; }
    const uint2* h0 = (const uint2*)(Hb + (size_t)(v0 ? r0 : 0) * 64);
    const uint2* h1 = (const uint2*)(Hb + (size_t)(v1 ? r1 : 0) * 64);
    for (int q = 0; q < 32; ++q) {
        uint2 ua = h0[q];
        uint2 ub = h1[q];
        float va[4] = {bflo(ua.x), bfhi(ua.x), bflo(ua.y), bfhi(ua.y)};
        float vb[4] = {bflo(ub.x), bfhi(ub.x), bflo(ub.y), bfhi(ub.y)};
#pragma unroll
        for (int j = 0; j < 4; ++j) {
            int k = 4 * q + j;
#pragma unroll
            for (int cq = 0; cq < GCP / 4; ++cq) {
                float4 wv = *(const float4*)&ws[k][4 * cq];
                acc0[4 * cq + 0] = fmaf(va[j], wv.x, acc0[4 * cq + 0]);
                acc0[4 * cq + 1] = fmaf(va[j], wv.y, acc0[4 * cq + 1]);
                acc0[4 * cq + 2] = fmaf(va[j], wv.z, acc0[4 * cq + 2]);
                acc0[4 * cq + 3] = fmaf(va[j], wv.w, acc0[4 * cq + 3]);
                acc1[4 * cq + 0] = fmaf(vb[j], wv.x, acc1[4 * cq + 0]);
                acc1[4 * cq + 1] = fmaf(vb[j], wv.y, acc1[4 * cq + 1]);
                acc1[4 * cq + 2] = fmaf(vb[j], wv.z, acc1[4 * cq + 2]);
                acc1[4 * cq + 3] = fmaf(vb[j], wv.w, acc1[4 * cq + 3]);
            }
        }
    }
    if (v0) {
#pragma unroll
        for (int c = 0; c < GCP; ++c) G[(size_t)r0 * GCP + c] = f2bf(acc0[c]);
    }
    if (v1) {
#pragma unroll
        for (int c = 0; c < GCP; ++c) G[(size_t)r1 * GCP + c] = f2bf(acc1[c]);
    }
}

// ---------------- layer-2 aggregate at width 48 + bias + log_softmax (r8-verified) ----------------

__global__ __launch_bounds__(256) void k_agg2(const unsigned short* __restrict__ G,
                                              float* __restrict__ out,
                                              const int* __restrict__ row_ptr,
                                              const int2* __restrict__ meta,
                                              const float* __restrict__ dinv,
                                              const float* __restrict__ b2, int n) {
    int wv = threadIdx.x >> 6;
    int lane = threadIdx.x & 63;
    int gl = (lane < GCP) ? lane : (GCP - 1);
    int d = blockIdx.x * 4 + wv;
    if (d >= n) return;
    float dd = dinv[d];
    int beg = row_ptr[d], end = row_ptr[d + 1];
    float a = dd * dd * bf2f(G[(size_t)d * GCP + gl]);
    int e = beg;
    for (; e + 16 <= end; e += 16) {
        int2 m[16];
        unsigned short u[16];
#pragma unroll
        for (int j = 0; j < 16; ++j) m[j] = meta[e + j];
#pragma unroll
        for (int j = 0; j < 16; ++j) u[j] = G[(size_t)m[j].x * GCP + gl];
#pragma unroll
        for (int j = 0; j < 16; ++j) a = fmaf(__int_as_float(m[j].y), bf2f(u[j]), a);
    }
    if (e + 8 <= end) {
        int2 m[8];
        unsigned short u[8];
#pragma unroll
        for (int j = 0; j < 8; ++j) m[j] = meta[e + j];
#pragma unroll
        for (int j = 0; j < 8; ++j) u[j] = G[(size_t)m[j].x * GCP + gl];
#pragma unroll
        for (int j = 0; j < 8; ++j) a = fmaf(__int_as_float(m[j].y), bf2f(u[j]), a);
        e += 8;
    }
    if (e + 4 <= end) {
        int2 m[4];
        unsigned short u[4];
#pragma unroll
        for (int j = 0; j < 4; ++j) m[j] = meta[e + j];
#pragma unroll
        for (int j = 0; j < 4; ++j) u[j] = G[(size_t)m[j].x * GCP + gl];
#pragma unroll
        for (int j = 0; j < 4; ++j) a = fmaf(__int_as_float(m[j].y), bf2f(u[j]), a);
        e += 4;
    }
    for (; e < end; ++e) {
        int2 m = meta[e];
        a = fmaf(__int_as_float(m.y), bf2f(G[(size_t)m.x * GCP + gl]), a);
    }
    float logit = (lane < GC) ? (a + b2[lane]) : -INFINITY;
    float mx = logit;
#pragma unroll
    for (int off = 32; off; off >>= 1) mx = fmaxf(mx, __shfl_xor(mx, off));
    float ex = (lane < GC) ? __expf(logit - mx) : 0.f;
    float sm = ex;
#pragma unroll
    for (int off = 32; off; off >>= 1) sm += __shfl_xor(sm, off);
    if (lane < GC) out[(size_t)d * GC + lane] = logit - mx - __logf(sm);
}

// ---------------- launch ----------------

static inline size_t alignup256(size_t x) { return (x + 255) & ~(size_t)255; }

extern "C" void kernel_launch(void* const* d_in, const int* in_sizes, int n_in,
                              void* d_out, int out_size, void* d_ws, size_t ws_size,
                              hipStream_t stream) {
    const float* x  = (const float*)d_in[0];
    const int*   ei = (const int*)d_in[1];
    const float* W1 = (const float*)d_in[2];
    const float* b1 = (const float*)d_in[3];
    const float* W2 = (const float*)d_in[4];
    const float* b2 = (const float*)d_in[5];
    float* out = (float*)d_out;

    const int n = in_sizes[0] / GK;   // 100000
    const int E = in_sizes[1] / 2;    // 1600000
    const int* src = ei;
    const int* dst = ei + E;

    char* w = (char*)d_ws;
    char* p;
    p = w; w += alignup256((size_t)n * 4);            float* dinv  = (float*)p;
    p = w; w += alignup256((size_t)n * 4);            int* counts  = (int*)p;
    p = w; w += alignup256((size_t)n * 4);            int* cursor  = (int*)p;
    p = w; w += alignup256((size_t)(n + 1) * 4);      int* row_ptr = (int*)p;
    p = w; w += alignup256(1024 * 4);                 int* bsum    = (int*)p;
    p = w; w += alignup256((size_t)E * 8);            int2* meta   = (int2*)p;
    p = w; w += alignup256((size_t)W1FN * 2);         unsigned short* W1F = (unsigned short*)p;
    p = w; w += alignup256((size_t)n * GH * 2);       unsigned short* bufA = (unsigned short*)p; // bf16 H1
    p = w; w += alignup256((size_t)n * GH * 2);       unsigned short* bufB = (unsigned short*)p; // bf16 relu(agg1)
    p = w; w += alignup256((size_t)n * GCP * 2);      unsigned short* G    = (unsigned short*)p; // bf16 H1relu@W2

    hipMemsetAsync(counts, 0, (size_t)n * 4, stream);

    int gN = (n + 255) / 256;
    int nb = (n + 1023) / 1024;
    int nbPrep = (W1FN + 255) / 256;          // 304
    int nbHist = (E / 4 + 255) / 256;         // 1563 (E divisible by 4)
    int nbG    = (n + 15) / 16;               // 6250

    k_pre<<<nbPrep + nbHist, 256, 0, stream>>>(W1, W1F, dst, counts, E, nbPrep);
    k_scan_a<<<nb, 256, 0, stream>>>(counts, row_ptr, bsum, n);
    k_scan_b<<<1, 256, 0, stream>>>(bsum, nb);
    k_scan_c<<<gN, 256, 0, stream>>>(row_ptr, bsum, counts, dinv, cursor, n, E);

    k_gemm1_fill<<<nbHist + nbG, 256, 0, stream>>>(x, W1F, bufA, n,
                                                   src, dst, dinv, cursor, meta, E, nbHist);
    k_agg1<<<(n + 3) / 4, 256, 0, stream>>>((const unsigned int*)bufA, (unsigned int*)bufB,
                                            row_ptr, meta, dinv, b1, n);
    k_gemm2t<<<(n + 511) / 512, 256, 0, stream>>>((const unsigned int*)bufB, W2, G, n);
    k_agg2<<<(n + 3) / 4, 256, 0, stream>>>(G, out, row_ptr, meta, dinv, b2, n);
}